// Round 3
// baseline (308.222 us; speedup 1.0000x reference)
//
#include <hip/hip_runtime.h>
#include <hip/hip_bf16.h>
#include <stdint.h>

#define N_Q   16384
#define N_CLS 1024
#define DIM_H 2048

typedef __bf16 bf16x8 __attribute__((ext_vector_type(8)));
typedef float  f32x4  __attribute__((ext_vector_type(4)));

__device__ __forceinline__ uint32_t f2bf(float f) {
    uint32_t u = __float_as_uint(f);
    u += 0x7fff + ((u >> 16) & 1);   // RNE
    return u >> 16;
}

// direct-to-LDS 16B staging; HW dest = wave-uniform base + lane*16
__device__ __forceinline__ void load_lds16(const __bf16* g, __bf16* l) {
    __builtin_amdgcn_global_load_lds(
        (const __attribute__((address_space(1))) uint32_t*)g,
        (__attribute__((address_space(3))) uint32_t*)l, 16, 0, 0);
}

// prepass 1: q_bf16[i] = bf16(q_f32[i]), 4 elems/thread
__global__ void cvt_q_kernel(const float* __restrict__ q,
                             uint16_t* __restrict__ o) {
    size_t e = ((size_t)blockIdx.x * 256 + threadIdx.x) * 4;
    float4 v = *(const float4*)(q + e);
    uint32_t lo = f2bf(v.x) | (f2bf(v.y) << 16);
    uint32_t hi = f2bf(v.z) | (f2bf(v.w) << 16);
    *(uint2*)(o + e) = make_uint2(lo, hi);
}

// prepass 2: cls_bf16[c*H+h] = bf16(cls_f32[c*H+h] * M_f32[h])
__global__ void scale_cls_kernel(const float* __restrict__ cls,
                                 const float* __restrict__ M,
                                 uint16_t* __restrict__ o) {
    size_t e = ((size_t)blockIdx.x * 256 + threadIdx.x) * 4;
    float4 c = *(const float4*)(cls + e);
    float4 m = *(const float4*)(M + (e & (DIM_H - 1)));
    uint32_t lo = f2bf(c.x * m.x) | (f2bf(c.y * m.y) << 16);
    uint32_t hi = f2bf(c.z * m.z) | (f2bf(c.w * m.w) << 16);
    *(uint2*)(o + e) = make_uint2(lo, hi);
}

// 128x128 tile, BK=64, 4 waves, each wave 64x64 via 4x4 mfma_f32_16x16x32_bf16.
// m97 layout: LDS row r (stride 64 elems = 128B), chunk p holds k-chunk p.
__global__ __launch_bounds__(256)
void gemm_bt_kernel(const uint16_t* __restrict__ Qp,   // (N,H) bf16
                    const uint16_t* __restrict__ Bp,   // (C,H) bf16, pre-scaled
                    float* __restrict__ Out) {         // (N,C) fp32
    __shared__ __align__(16) __bf16 As[128 * 64];
    __shared__ __align__(16) __bf16 Bs[128 * 64];

    const int tid  = threadIdx.x;
    const int lane = tid & 63;
    const int wave = tid >> 6;
    const int row0 = blockIdx.y * 128;      // query rows
    const int col0 = blockIdx.x * 128;      // class cols
    const int wm   = (wave >> 1) * 64;
    const int wn   = (wave & 1) * 64;
    const int frow = lane & 15;
    const int fq   = lane >> 4;

    const __bf16* Q = (const __bf16*)Qp;
    const __bf16* B = (const __bf16*)Bp;

    f32x4 acc[4][4] = {};

    for (int k0 = 0; k0 < DIM_H; k0 += 64) {
        // ---- stage 16KB A-tile + 16KB B-tile ----
#pragma unroll
        for (int i = 0; i < 4; ++i) {
            const int chunkbase = (i * 4 + wave) * 64;   // wave-uniform
            const int pg = chunkbase + lane;
            const int r  = pg >> 3;                      // tile row
            const int cc = (pg & 7) * 8;                 // k-offset (elems)
            load_lds16(Q + (size_t)(row0 + r) * DIM_H + k0 + cc, &As[chunkbase * 8]);
            load_lds16(B + (size_t)(col0 + r) * DIM_H + k0 + cc, &Bs[chunkbase * 8]);
        }
        __syncthreads();

        // ---- compute: 2 k-steps x 16 MFMA ----
#pragma unroll
        for (int ks = 0; ks < 2; ++ks) {
            const int pk = (ks * 4 + fq) * 8;            // k-offset within row
            bf16x8 af[4], bfr[4];
#pragma unroll
            for (int t = 0; t < 4; ++t) {
                af[t]  = *(const bf16x8*)&As[(wm + t * 16 + frow) * 64 + pk];
                bfr[t] = *(const bf16x8*)&Bs[(wn + t * 16 + frow) * 64 + pk];
            }
#pragma unroll
            for (int i = 0; i < 4; ++i)
#pragma unroll
                for (int j = 0; j < 4; ++j)
                    acc[i][j] = __builtin_amdgcn_mfma_f32_16x16x32_bf16(
                        af[i], bfr[j], acc[i][j], 0, 0, 0);
        }
        __syncthreads();
    }

    // ---- epilogue: C/D layout col=lane&15, row=(lane>>4)*4+reg; fp32 out ----
#pragma unroll
    for (int i = 0; i < 4; ++i) {
#pragma unroll
        for (int j = 0; j < 4; ++j) {
            const int row = row0 + wm + i * 16 + fq * 4;
            const int col = col0 + wn + j * 16 + frow;
#pragma unroll
            for (int r = 0; r < 4; ++r)
                Out[(size_t)(row + r) * N_CLS + col] = acc[i][j][r];
        }
    }
}

// correctness fallback (fp32 end-to-end) if workspace is too small
__global__ void naive_kernel(const float* __restrict__ Q,
                             const float* __restrict__ C,
                             const float* __restrict__ M,
                             float* __restrict__ Out) {
    size_t idx = (size_t)blockIdx.x * 256 + threadIdx.x;
    int n = (int)(idx >> 10), c = (int)(idx & (N_CLS - 1));
    float s = 0.f;
    for (int h = 0; h < DIM_H; ++h)
        s += Q[(size_t)n * DIM_H + h] * C[(size_t)c * DIM_H + h] * M[h];
    Out[idx] = s;
}

extern "C" void kernel_launch(void* const* d_in, const int* in_sizes, int n_in,
                              void* d_out, int out_size, void* d_ws, size_t ws_size,
                              hipStream_t stream) {
    // identify inputs by element count (robust to ordering)
    const float* cls = (const float*)d_in[0];   // (C,H)  = 2,097,152
    const float* q   = (const float*)d_in[1];   // (N,H)  = 33,554,432
    const float* M   = (const float*)d_in[2];   // (H,1)  = 2,048
    for (int i = 0; i < n_in; ++i) {
        if      (in_sizes[i] == N_CLS * DIM_H) cls = (const float*)d_in[i];
        else if (in_sizes[i] == N_Q * DIM_H)   q   = (const float*)d_in[i];
        else if (in_sizes[i] == DIM_H)         M   = (const float*)d_in[i];
    }
    float* out = (float*)d_out;

    const size_t cls_bytes = (size_t)N_CLS * DIM_H * sizeof(uint16_t);  //  4 MB
    const size_t q_bytes   = (size_t)N_Q * DIM_H * sizeof(uint16_t);    // 67 MB
    if (ws_size >= cls_bytes + q_bytes) {
        uint16_t* cls_bf = (uint16_t*)d_ws;
        uint16_t* q_bf   = (uint16_t*)((char*)d_ws + cls_bytes);
        scale_cls_kernel<<<(N_CLS * DIM_H) / (256 * 4), 256, 0, stream>>>(cls, M, cls_bf);
        cvt_q_kernel<<<(N_Q * DIM_H) / (256 * 4), 256, 0, stream>>>(q, q_bf);
        dim3 grid(N_CLS / 128, N_Q / 128);
        gemm_bt_kernel<<<grid, 256, 0, stream>>>(q_bf, cls_bf, out);
    } else {
        naive_kernel<<<(unsigned)(((size_t)N_Q * N_CLS) / 256), 256, 0, stream>>>(q, cls, M, out);
    }
}

// Round 4
// 300.707 us; speedup vs baseline: 1.0250x; 1.0250x over previous
//
#include <hip/hip_runtime.h>
#include <hip/hip_bf16.h>
#include <stdint.h>

#define N_Q   16384
#define N_CLS 1024
#define DIM_H 2048

typedef __bf16 bf16x8 __attribute__((ext_vector_type(8)));
typedef float  f32x4  __attribute__((ext_vector_type(4)));

__device__ __forceinline__ uint32_t f2bf(float f) {
    uint32_t u = __float_as_uint(f);
    u += 0x7fff + ((u >> 16) & 1);   // RNE
    return u >> 16;
}
// pack two fp32 -> two bf16 (round-to-nearest, ties away): 2 adds + 1 perm
__device__ __forceinline__ uint32_t pk2(float a, float b) {
    uint32_t ua = __float_as_uint(a) + 0x8000u;
    uint32_t ub = __float_as_uint(b) + 0x8000u;
    return (ua >> 16) | (ub & 0xFFFF0000u);
}

// direct-to-LDS 16B staging; HW dest = wave-uniform base + lane*16
__device__ __forceinline__ void load_lds16(const __bf16* g, __bf16* l) {
    __builtin_amdgcn_global_load_lds(
        (const __attribute__((address_space(1))) uint32_t*)g,
        (__attribute__((address_space(3))) uint32_t*)l, 16, 0, 0);
}

// prepass: cls_bf16[c*H+h] = bf16(cls_f32[c*H+h] * M_f32[h])  (4 MB out)
__global__ void scale_cls_kernel(const float* __restrict__ cls,
                                 const float* __restrict__ M,
                                 uint16_t* __restrict__ o) {
    size_t e = ((size_t)blockIdx.x * 256 + threadIdx.x) * 4;
    float4 c = *(const float4*)(cls + e);
    float4 m = *(const float4*)(M + (e & (DIM_H - 1)));
    uint32_t lo = f2bf(c.x * m.x) | (f2bf(c.y * m.y) << 16);
    uint32_t hi = f2bf(c.z * m.z) | (f2bf(c.w * m.w) << 16);
    *(uint2*)(o + e) = make_uint2(lo, hi);
}

// 128x128 tile, BK=64, 4 waves, 4x4 mfma_f32_16x16x32_bf16 per wave.
// A (q, fp32) converted in-kernel: dwordx4 loads -> pk2 -> ds_write_b128.
// B (cls, bf16 pre-scaled) staged via global_load_lds.
// LDS XOR-8 swizzle: 16B chunk at (row r, pos p) holds k-chunk p^(r&7).
// Grid (x=128 rows fastest, y=8 cols): col-twins share XCD (b%8 = row%8).
__global__ __launch_bounds__(256)
void gemm_fused_kernel(const float* __restrict__ Q,      // (N,H) fp32
                       const uint16_t* __restrict__ Bp,  // (C,H) bf16
                       float* __restrict__ Out) {        // (N,C) fp32
    __shared__ __align__(16) __bf16 As[128 * 64];
    __shared__ __align__(16) __bf16 Bs[128 * 64];

    const int tid  = threadIdx.x;
    const int lane = tid & 63;
    const int wave = tid >> 6;
    const int row0 = blockIdx.x * 128;      // query rows (fastest)
    const int col0 = blockIdx.y * 128;      // class cols
    const int wm   = (wave >> 1) * 64;
    const int wn   = (wave & 1) * 64;
    const int frow = lane & 15;
    const int fq   = lane >> 4;

    const __bf16* B = (const __bf16*)Bp;

    f32x4 acc[4][4] = {};

    for (int k0 = 0; k0 < DIM_H; k0 += 64) {
        // ---- B tile: async global->LDS, swizzled global chunk choice ----
#pragma unroll
        for (int i = 0; i < 4; ++i) {
            const int chunkbase = (i * 4 + wave) * 64;   // wave-uniform
            const int c = chunkbase + lane;              // LDS chunk index
            const int r = c >> 3;                        // tile row
            const int g = (c & 7) ^ (r & 7);             // global k-chunk
            load_lds16(B + (size_t)(col0 + r) * DIM_H + k0 + g * 8,
                       &Bs[chunkbase * 8]);
        }
        // ---- A tile: fp32 load -> bf16 pack -> swizzled ds_write_b128 ----
#pragma unroll
        for (int i = 0; i < 4; ++i) {
            const int u  = tid + 256 * i;                // unit = 8 elems
            const int r  = u >> 3;
            const int kc = u & 7;
            const float* src = Q + (size_t)(row0 + r) * DIM_H + k0 + kc * 8;
            float4 a = *(const float4*)src;
            float4 b = *(const float4*)(src + 4);
            uint4 w = make_uint4(pk2(a.x, a.y), pk2(a.z, a.w),
                                 pk2(b.x, b.y), pk2(b.z, b.w));
            const int p = kc ^ (r & 7);
            *(uint4*)&As[r * 64 + p * 8] = w;
        }
        __syncthreads();

        // ---- compute: 2 k-steps x 16 MFMA ----
#pragma unroll
        for (int ks = 0; ks < 2; ++ks) {
            bf16x8 af[4], bfr[4];
#pragma unroll
            for (int t = 0; t < 4; ++t) {
                const int ra = wm + t * 16 + frow;
                const int pa = (((ks * 4 + fq) ^ (ra & 7))) * 8;
                af[t] = *(const bf16x8*)&As[ra * 64 + pa];
                const int rb = wn + t * 16 + frow;
                const int pb = (((ks * 4 + fq) ^ (rb & 7))) * 8;
                bfr[t] = *(const bf16x8*)&Bs[rb * 64 + pb];
            }
#pragma unroll
            for (int i = 0; i < 4; ++i)
#pragma unroll
                for (int j = 0; j < 4; ++j)
                    acc[i][j] = __builtin_amdgcn_mfma_f32_16x16x32_bf16(
                        af[i], bfr[j], acc[i][j], 0, 0, 0);
        }
        __syncthreads();
    }

    // ---- epilogue: C/D layout col=lane&15, row=(lane>>4)*4+reg; fp32 out ----
#pragma unroll
    for (int i = 0; i < 4; ++i) {
#pragma unroll
        for (int j = 0; j < 4; ++j) {
            const int row = row0 + wm + i * 16 + fq * 4;
            const int col = col0 + wn + j * 16 + frow;
#pragma unroll
            for (int r = 0; r < 4; ++r)
                Out[(size_t)(row + r) * N_CLS + col] = acc[i][j][r];
        }
    }
}

// correctness fallback (fp32 end-to-end) if workspace is too small
__global__ void naive_kernel(const float* __restrict__ Q,
                             const float* __restrict__ C,
                             const float* __restrict__ M,
                             float* __restrict__ Out) {
    size_t idx = (size_t)blockIdx.x * 256 + threadIdx.x;
    int n = (int)(idx >> 10), c = (int)(idx & (N_CLS - 1));
    float s = 0.f;
    for (int h = 0; h < DIM_H; ++h)
        s += Q[(size_t)n * DIM_H + h] * C[(size_t)c * DIM_H + h] * M[h];
    Out[idx] = s;
}

extern "C" void kernel_launch(void* const* d_in, const int* in_sizes, int n_in,
                              void* d_out, int out_size, void* d_ws, size_t ws_size,
                              hipStream_t stream) {
    const float* cls = (const float*)d_in[0];   // (C,H)  = 2,097,152
    const float* q   = (const float*)d_in[1];   // (N,H)  = 33,554,432
    const float* M   = (const float*)d_in[2];   // (H,1)  = 2,048
    for (int i = 0; i < n_in; ++i) {
        if      (in_sizes[i] == N_CLS * DIM_H) cls = (const float*)d_in[i];
        else if (in_sizes[i] == N_Q * DIM_H)   q   = (const float*)d_in[i];
        else if (in_sizes[i] == DIM_H)         M   = (const float*)d_in[i];
    }
    float* out = (float*)d_out;

    const size_t cls_bytes = (size_t)N_CLS * DIM_H * sizeof(uint16_t);  // 4 MB
    if (ws_size >= cls_bytes) {
        uint16_t* cls_bf = (uint16_t*)d_ws;
        scale_cls_kernel<<<(N_CLS * DIM_H) / (256 * 4), 256, 0, stream>>>(cls, M, cls_bf);
        dim3 grid(N_Q / 128, N_CLS / 128);   // x = rows (fastest), y = cols
        gemm_fused_kernel<<<grid, 256, 0, stream>>>(q, cls_bf, out);
    } else {
        naive_kernel<<<(unsigned)(((size_t)N_Q * N_CLS) / 256), 256, 0, stream>>>(q, cls, M, out);
    }
}

// Round 5
// 294.042 us; speedup vs baseline: 1.0482x; 1.0227x over previous
//
#include <hip/hip_runtime.h>
#include <hip/hip_bf16.h>
#include <stdint.h>

#define N_Q   16384
#define N_CLS 1024
#define DIM_H 2048

typedef __bf16 bf16x8 __attribute__((ext_vector_type(8)));
typedef float  f32x4  __attribute__((ext_vector_type(4)));

__device__ __forceinline__ uint32_t f2bf(float f) {
    uint32_t u = __float_as_uint(f);
    u += 0x7fff + ((u >> 16) & 1);   // RNE
    return u >> 16;
}
// pack two fp32 -> two bf16 (round-to-nearest ties-away): 2 adds + 1 merge
__device__ __forceinline__ uint32_t pk2(float a, float b) {
    uint32_t ua = __float_as_uint(a) + 0x8000u;
    uint32_t ub = __float_as_uint(b) + 0x8000u;
    return (ua >> 16) | (ub & 0xFFFF0000u);
}

// direct-to-LDS 16B staging; HW dest = wave-uniform base + lane*16
__device__ __forceinline__ void load_lds16(const __bf16* g, __bf16* l) {
    __builtin_amdgcn_global_load_lds(
        (const __attribute__((address_space(1))) uint32_t*)g,
        (__attribute__((address_space(3))) uint32_t*)l, 16, 0, 0);
}

// prepass 1: q_bf16[i] = bf16(q_f32[i]), 8 elems/thread (201 MB stream)
__global__ void cvt_q_kernel(const float* __restrict__ q,
                             uint16_t* __restrict__ o) {
    size_t e = ((size_t)blockIdx.x * 256 + threadIdx.x) * 8;
    float4 a = *(const float4*)(q + e);
    float4 b = *(const float4*)(q + e + 4);
    *(uint4*)(o + e) = make_uint4(pk2(a.x, a.y), pk2(a.z, a.w),
                                  pk2(b.x, b.y), pk2(b.z, b.w));
}

// prepass 2: cls_bf16[c*H+h] = bf16(cls_f32[c*H+h] * M_f32[h])  (4 MB out)
__global__ void scale_cls_kernel(const float* __restrict__ cls,
                                 const float* __restrict__ M,
                                 uint16_t* __restrict__ o) {
    size_t e = ((size_t)blockIdx.x * 256 + threadIdx.x) * 4;
    float4 c = *(const float4*)(cls + e);
    float4 m = *(const float4*)(M + (e & (DIM_H - 1)));
    uint32_t lo = f2bf(c.x * m.x) | (f2bf(c.y * m.y) << 16);
    uint32_t hi = f2bf(c.z * m.z) | (f2bf(c.w * m.w) << 16);
    *(uint2*)(o + e) = make_uint2(lo, hi);
}

// 128x128 tile, BK=64, 4 waves, 4x4 mfma_f32_16x16x32_bf16 per wave.
// Both tiles staged via async global_load_lds (R3 structure).
// LDS XOR-8 swizzle (R4-verified): chunk at (row r, pos p) holds k-chunk p^(r&7).
// Block mapping: xcd=b&7 owns row-panels 16*xcd..16*xcd+15 across all 8 cols.
__global__ __launch_bounds__(256)
void gemm_bt_kernel(const uint16_t* __restrict__ Qp,   // (N,H) bf16 (ws)
                    const uint16_t* __restrict__ Bp,   // (C,H) bf16 pre-scaled
                    float* __restrict__ Out) {         // (N,C) fp32
    __shared__ __align__(16) __bf16 As[128 * 64];
    __shared__ __align__(16) __bf16 Bs[128 * 64];

    const int tid  = threadIdx.x;
    const int lane = tid & 63;
    const int wave = tid >> 6;

    const int b    = blockIdx.x;            // 0..1023
    const int xcd  = b & 7;
    const int t    = b >> 3;                // 0..127
    const int row0 = (xcd * 16 + (t >> 3)) * 128;   // query rows
    const int col0 = (t & 7) * 128;                 // class cols

    const int wm   = (wave >> 1) * 64;
    const int wn   = (wave & 1) * 64;
    const int frow = lane & 15;
    const int fq   = lane >> 4;

    const __bf16* Q = (const __bf16*)Qp;
    const __bf16* B = (const __bf16*)Bp;

    f32x4 acc[4][4] = {};

    for (int k0 = 0; k0 < DIM_H; k0 += 64) {
        // ---- stage 16KB A + 16KB B, swizzled global chunk choice ----
#pragma unroll
        for (int i = 0; i < 4; ++i) {
            const int chunkbase = (i * 4 + wave) * 64;   // wave-uniform
            const int c = chunkbase + lane;              // LDS chunk index
            const int r = c >> 3;                        // tile row
            const int g = (c & 7) ^ (r & 7);             // global k-chunk
            load_lds16(Q + (size_t)(row0 + r) * DIM_H + k0 + g * 8,
                       &As[chunkbase * 8]);
            load_lds16(B + (size_t)(col0 + r) * DIM_H + k0 + g * 8,
                       &Bs[chunkbase * 8]);
        }
        __syncthreads();

        // ---- compute: 2 k-steps x 16 MFMA, swizzled fragment reads ----
#pragma unroll
        for (int ks = 0; ks < 2; ++ks) {
            bf16x8 af[4], bfr[4];
#pragma unroll
            for (int tt = 0; tt < 4; ++tt) {
                const int ra = wm + tt * 16 + frow;
                const int pa = ((ks * 4 + fq) ^ (ra & 7)) * 8;
                af[tt] = *(const bf16x8*)&As[ra * 64 + pa];
                const int rb = wn + tt * 16 + frow;
                const int pb = ((ks * 4 + fq) ^ (rb & 7)) * 8;
                bfr[tt] = *(const bf16x8*)&Bs[rb * 64 + pb];
            }
#pragma unroll
            for (int i = 0; i < 4; ++i)
#pragma unroll
                for (int j = 0; j < 4; ++j)
                    acc[i][j] = __builtin_amdgcn_mfma_f32_16x16x32_bf16(
                        af[i], bfr[j], acc[i][j], 0, 0, 0);
        }
        __syncthreads();
    }

    // ---- epilogue: C/D layout col=lane&15, row=(lane>>4)*4+reg; fp32 out ----
#pragma unroll
    for (int i = 0; i < 4; ++i) {
#pragma unroll
        for (int j = 0; j < 4; ++j) {
            const int row = row0 + wm + i * 16 + fq * 4;
            const int col = col0 + wn + j * 16 + frow;
#pragma unroll
            for (int r = 0; r < 4; ++r)
                Out[(size_t)(row + r) * N_CLS + col] = acc[i][j][r];
        }
    }
}

// correctness fallback (fp32 end-to-end) if workspace is too small
__global__ void naive_kernel(const float* __restrict__ Q,
                             const float* __restrict__ C,
                             const float* __restrict__ M,
                             float* __restrict__ Out) {
    size_t idx = (size_t)blockIdx.x * 256 + threadIdx.x;
    int n = (int)(idx >> 10), c = (int)(idx & (N_CLS - 1));
    float s = 0.f;
    for (int h = 0; h < DIM_H; ++h)
        s += Q[(size_t)n * DIM_H + h] * C[(size_t)c * DIM_H + h] * M[h];
    Out[idx] = s;
}

extern "C" void kernel_launch(void* const* d_in, const int* in_sizes, int n_in,
                              void* d_out, int out_size, void* d_ws, size_t ws_size,
                              hipStream_t stream) {
    const float* cls = (const float*)d_in[0];   // (C,H)  = 2,097,152
    const float* q   = (const float*)d_in[1];   // (N,H)  = 33,554,432
    const float* M   = (const float*)d_in[2];   // (H,1)  = 2,048
    for (int i = 0; i < n_in; ++i) {
        if      (in_sizes[i] == N_CLS * DIM_H) cls = (const float*)d_in[i];
        else if (in_sizes[i] == N_Q * DIM_H)   q   = (const float*)d_in[i];
        else if (in_sizes[i] == DIM_H)         M   = (const float*)d_in[i];
    }
    float* out = (float*)d_out;

    const size_t cls_bytes = (size_t)N_CLS * DIM_H * sizeof(uint16_t);  //  4 MB
    const size_t q_bytes   = (size_t)N_Q * DIM_H * sizeof(uint16_t);    // 67 MB
    if (ws_size >= cls_bytes + q_bytes) {
        uint16_t* cls_bf = (uint16_t*)d_ws;
        uint16_t* q_bf   = (uint16_t*)((char*)d_ws + cls_bytes);
        scale_cls_kernel<<<(N_CLS * DIM_H) / (256 * 4), 256, 0, stream>>>(cls, M, cls_bf);
        cvt_q_kernel<<<(N_Q * DIM_H) / (256 * 8), 256, 0, stream>>>(q, q_bf);
        gemm_bt_kernel<<<(N_Q / 128) * (N_CLS / 128), 256, 0, stream>>>(q_bf, cls_bf, out);
    } else {
        naive_kernel<<<(unsigned)(((size_t)N_Q * N_CLS) / 256), 256, 0, stream>>>(q, cls, M, out);
    }
}